// Round 1
// baseline (180.575 us; speedup 1.0000x reference)
//
#include <hip/hip_runtime.h>
#include <hip/hip_bf16.h>

// Problem constants
#define BATCH  16384
#define DIM    512
#define NLAYER 3
#define NEXP   4
#define RANK   128

typedef __bf16 bf16_t;
typedef bf16_t bf16x8 __attribute__((ext_vector_type(8)));
typedef bf16_t bf16x4 __attribute__((ext_vector_type(4)));
typedef float  f32x4  __attribute__((ext_vector_type(4)));

__device__ __forceinline__ float tanh_fast(float x) {
    // tanh(x) = 1 - 2/(1+e^{2x}); exact at +-inf, ~1ulp from v_exp/v_rcp
    float e = __expf(2.0f * x);
    return 1.0f - 2.0f * __builtin_amdgcn_rcpf(e + 1.0f);
}

// ---------------- prep kernels (once per launch, tiny) ----------------

__global__ void convert_f32_bf16(const float* __restrict__ in,
                                 bf16_t* __restrict__ out, int n) {
    int i = blockIdx.x * 256 + threadIdx.x;
    if (i < n) out[i] = (bf16_t)in[i];
}

// Vt[le][r][d] = Vs[le][d][r]  (le = l*E+e), output-contiguous
__global__ void transpose_v(const float* __restrict__ Vs,
                            bf16_t* __restrict__ Vt) {
    int i = blockIdx.x * 256 + threadIdx.x;      // < 12*128*512 = 786432
    int d  = i & (DIM - 1);
    int r  = (i >> 9) & (RANK - 1);
    int le = i >> 16;
    Vt[i] = (bf16_t)Vs[((size_t)le * DIM + d) * RANK + r];
}

// ---------------- k1: XC = tanh( tanh(XL @ V_e) @ C_e^T ) ----------------
// grid (BATCH/128, NEXP), block 256 (4 waves, 2x2 wave grid of 64x64)

__global__ __launch_bounds__(256, 2)
void k1_vc(const float* __restrict__ A,      // xl (B, 512) f32
           const bf16_t* __restrict__ Vt,    // [E][R][D] this layer (transposed)
           const bf16_t* __restrict__ Cl,    // [E][R][R] this layer
           bf16_t* __restrict__ XC)          // (B, 512) bf16 out
{
    const int m0   = blockIdx.x * 128;
    const int e    = blockIdx.y;
    const int tid  = threadIdx.x;
    const int lane = tid & 63;
    const int wave = tid >> 6;
    const int wm = wave >> 1, wn = wave & 1;
    const int lr = lane & 15;   // row (A) / col (B,D) within 16
    const int lg = lane >> 4;   // k-group

    __shared__ __align__(16) char smem[69632];
    bf16_t* As = (bf16_t*)smem;              // [128][72] phase 1
    bf16_t* Bs = (bf16_t*)(smem + 18432);    // [128][72] phase 1
    bf16_t* Xs = (bf16_t*)smem;              // [128][136] phase 2 (XV as A)
    bf16_t* Cs = (bf16_t*)(smem + 34816);    // [128][136] phase 2 (C^T as Bt)

    const bf16_t* Ve = Vt + (size_t)e * RANK * DIM;

    f32x4 acc[4][4] = {};

    // ---- phase 1: XV = XL @ V_e  (M=128,N=128,K=512) ----
    for (int kc = 0; kc < DIM; kc += 64) {
        #pragma unroll
        for (int i = 0; i < 8; ++i) {                 // A: f32 -> bf16
            int q = tid + 256 * i;                    // 0..2047
            int row = q >> 4, c4 = (q & 15) << 2;
            float4 v = *(const float4*)(A + (size_t)(m0 + row) * DIM + kc + c4);
            bf16x4 b4 = { (bf16_t)v.x, (bf16_t)v.y, (bf16_t)v.z, (bf16_t)v.w };
            *(bf16x4*)(As + row * 72 + c4) = b4;
        }
        #pragma unroll
        for (int i = 0; i < 4; ++i) {                 // Bt[r][d] rows, contiguous
            int q = tid + 256 * i;                    // 0..1023
            int row = q >> 3, c8 = (q & 7) << 3;
            bf16x8 v = *(const bf16x8*)(Ve + (size_t)row * DIM + kc + c8);
            *(bf16x8*)(Bs + row * 72 + c8) = v;
        }
        __syncthreads();
        #pragma unroll
        for (int ks = 0; ks < 64; ks += 32) {
            bf16x8 af[4], bfv[4];
            #pragma unroll
            for (int mi = 0; mi < 4; ++mi)
                af[mi] = *(const bf16x8*)(As + (wm*64 + mi*16 + lr) * 72 + ks + lg*8);
            #pragma unroll
            for (int ni = 0; ni < 4; ++ni)
                bfv[ni] = *(const bf16x8*)(Bs + (wn*64 + ni*16 + lr) * 72 + ks + lg*8);
            #pragma unroll
            for (int mi = 0; mi < 4; ++mi)
                #pragma unroll
                for (int ni = 0; ni < 4; ++ni)
                    acc[mi][ni] = __builtin_amdgcn_mfma_f32_16x16x32_bf16(
                        af[mi], bfv[ni], acc[mi][ni], 0, 0, 0);
        }
        __syncthreads();
    }

    // ---- tanh, write XV into Xs in A-layout (bf16) ----
    #pragma unroll
    for (int mi = 0; mi < 4; ++mi)
        #pragma unroll
        for (int ni = 0; ni < 4; ++ni)
            #pragma unroll
            for (int j = 0; j < 4; ++j) {
                int m  = wm*64 + mi*16 + lg*4 + j;
                int k2 = wn*64 + ni*16 + lr;
                Xs[m * 136 + k2] = (bf16_t)tanh_fast(acc[mi][ni][j]);
            }

    // stage C^T: Cs[r][s] = C[e][r][s] (row-contiguous)
    const bf16_t* Ce = Cl + (size_t)e * RANK * RANK;
    #pragma unroll
    for (int i = 0; i < 8; ++i) {
        int q = tid + 256 * i;                        // 0..2047
        int row = q >> 4, c8 = (q & 15) << 3;
        bf16x8 v = *(const bf16x8*)(Ce + row * RANK + c8);
        *(bf16x8*)(Cs + row * 136 + c8) = v;
    }
    __syncthreads();

    // ---- phase 2: XC = XV @ C^T  (M=128,N=128,K=128) ----
    f32x4 acc2[4][4] = {};
    #pragma unroll
    for (int ks = 0; ks < 128; ks += 32) {
        bf16x8 af[4], bfv[4];
        #pragma unroll
        for (int mi = 0; mi < 4; ++mi)
            af[mi] = *(const bf16x8*)(Xs + (wm*64 + mi*16 + lr) * 136 + ks + lg*8);
        #pragma unroll
        for (int ni = 0; ni < 4; ++ni)
            bfv[ni] = *(const bf16x8*)(Cs + (wn*64 + ni*16 + lr) * 136 + ks + lg*8);
        #pragma unroll
        for (int mi = 0; mi < 4; ++mi)
            #pragma unroll
            for (int ni = 0; ni < 4; ++ni)
                acc2[mi][ni] = __builtin_amdgcn_mfma_f32_16x16x32_bf16(
                    af[mi], bfv[ni], acc2[mi][ni], 0, 0, 0);
    }

    // ---- tanh + global write of XC (bf16) ----
    #pragma unroll
    for (int mi = 0; mi < 4; ++mi)
        #pragma unroll
        for (int ni = 0; ni < 4; ++ni)
            #pragma unroll
            for (int j = 0; j < 4; ++j) {
                int m = wm*64 + mi*16 + lg*4 + j;
                int c = wn*64 + ni*16 + lr;
                XC[(size_t)(m0 + m) * DIM + e * RANK + c] =
                    (bf16_t)tanh_fast(acc2[mi][ni][j]);
            }
}

// ---------------- k2: out = xl + x0 * (XC @ Ucat + E*bias) ----------------
// grid (BATCH/128, DIM/128), block 256

__global__ __launch_bounds__(256, 2)
void k2_u(const bf16_t* __restrict__ XC,   // (B, 512) bf16
          const bf16_t* __restrict__ Ul,   // [E][D][R] this layer
          const float* __restrict__ x0,    // (B, 512)
          const float* __restrict__ xl,    // (B, 512) layer input
          const float* __restrict__ bias,  // [D] this layer
          float* __restrict__ out)         // (B, 512)
{
    const int m0   = blockIdx.x * 128;
    const int n0   = blockIdx.y * 128;
    const int tid  = threadIdx.x;
    const int lane = tid & 63;
    const int wave = tid >> 6;
    const int wm = wave >> 1, wn = wave & 1;
    const int lr = lane & 15;
    const int lg = lane >> 4;

    __shared__ __align__(16) char smem[36864];
    bf16_t* As = (bf16_t*)smem;              // [128][72]
    bf16_t* Bs = (bf16_t*)(smem + 18432);    // [128][72]

    f32x4 acc[4][4] = {};

    for (int kc = 0; kc < 512; kc += 64) {
        const int e  = kc >> 7;
        const int r0 = kc & 127;
        #pragma unroll
        for (int i = 0; i < 4; ++i) {                 // A: XC rows (bf16)
            int q = tid + 256 * i;
            int row = q >> 3, c8 = (q & 7) << 3;
            bf16x8 v = *(const bf16x8*)(XC + (size_t)(m0 + row) * DIM + kc + c8);
            *(bf16x8*)(As + row * 72 + c8) = v;
        }
        #pragma unroll
        for (int i = 0; i < 4; ++i) {                 // Bt[d][r] = U[e][d][r], contiguous
            int q = tid + 256 * i;
            int row = q >> 3, c8 = (q & 7) << 3;
            bf16x8 v = *(const bf16x8*)(Ul + ((size_t)e * DIM + n0 + row) * RANK + r0 + c8);
            *(bf16x8*)(Bs + row * 72 + c8) = v;
        }
        __syncthreads();
        #pragma unroll
        for (int ks = 0; ks < 64; ks += 32) {
            bf16x8 af[4], bfv[4];
            #pragma unroll
            for (int mi = 0; mi < 4; ++mi)
                af[mi] = *(const bf16x8*)(As + (wm*64 + mi*16 + lr) * 72 + ks + lg*8);
            #pragma unroll
            for (int ni = 0; ni < 4; ++ni)
                bfv[ni] = *(const bf16x8*)(Bs + (wn*64 + ni*16 + lr) * 72 + ks + lg*8);
            #pragma unroll
            for (int mi = 0; mi < 4; ++mi)
                #pragma unroll
                for (int ni = 0; ni < 4; ++ni)
                    acc[mi][ni] = __builtin_amdgcn_mfma_f32_16x16x32_bf16(
                        af[mi], bfv[ni], acc[mi][ni], 0, 0, 0);
        }
        __syncthreads();
    }

    // epilogue: out = xl + x0 * (acc + E*bias)   (gate == 1 exactly)
    #pragma unroll
    for (int mi = 0; mi < 4; ++mi)
        #pragma unroll
        for (int ni = 0; ni < 4; ++ni)
            #pragma unroll
            for (int j = 0; j < 4; ++j) {
                int m = m0 + wm*64 + mi*16 + lg*4 + j;
                int n = n0 + wn*64 + ni*16 + lr;
                size_t idx = (size_t)m * DIM + n;
                out[idx] = xl[idx] + x0[idx] * (acc[mi][ni][j] + 4.0f * bias[n]);
            }
}

// ---------------- host ----------------

extern "C" void kernel_launch(void* const* d_in, const int* in_sizes, int n_in,
                              void* d_out, int out_size, void* d_ws, size_t ws_size,
                              hipStream_t stream) {
    const float* x  = (const float*)d_in[0];   // (B, D)
    const float* Us = (const float*)d_in[1];   // (L, E, D, R)
    const float* Cw = (const float*)d_in[2];   // (L, E, R, R)
    const float* Vs = (const float*)d_in[3];   // (L, E, D, R)
    // d_in[4] = G: gate is softmax over singleton axis == 1.0 -> unused
    const float* bb = (const float*)d_in[5];   // (L, D)
    float* out = (float*)d_out;

    const int nV = NLAYER * NEXP * DIM * RANK;   // 786432
    const int nC = NLAYER * NEXP * RANK * RANK;  // 196608

    char* w = (char*)d_ws;
    bf16_t* Vt = (bf16_t*)w;                                   // [L][E][R][D]
    bf16_t* Ub = (bf16_t*)(w + (size_t)nV * 2);                // [L][E][D][R]
    bf16_t* Cb = (bf16_t*)(w + (size_t)nV * 4);                // [L][E][R][R]
    bf16_t* XC = (bf16_t*)(w + (size_t)nV * 4 + (size_t)nC * 2); // (B, 512)

    transpose_v<<<nV / 256, 256, 0, stream>>>(Vs, Vt);
    convert_f32_bf16<<<nV / 256, 256, 0, stream>>>(Us, Ub, nV);
    convert_f32_bf16<<<nC / 256, 256, 0, stream>>>(Cw, Cb, nC);

    for (int l = 0; l < NLAYER; ++l) {
        const float* xl = (l == 0) ? x : out;
        k1_vc<<<dim3(BATCH / 128, NEXP), 256, 0, stream>>>(
            xl,
            Vt + (size_t)l * NEXP * RANK * DIM,
            Cb + (size_t)l * NEXP * RANK * RANK,
            XC);
        k2_u<<<dim3(BATCH / 128, DIM / 128), 256, 0, stream>>>(
            XC,
            Ub + (size_t)l * NEXP * DIM * RANK,
            x, xl, bb + (size_t)l * DIM,
            out);
    }
}